// Round 1
// baseline (769.050 us; speedup 1.0000x reference)
//
#include <hip/hip_runtime.h>
#include <hip/hip_bf16.h>
#include <cstdint>

// Problem constants (bsz=8, h=1024, seq=1024, K=2 taps)
#define HSZ   1024
#define SEQ   1024
#define NTOT  8192      // bsz*seq
#define K2    2048      // 2*h (i,tap interleaved)
#define LDA   40        // shorts per A LDS row (32 data + 8 pad -> 80B stride, 2-way banks)
#define LDB   40

typedef __attribute__((ext_vector_type(8))) short bf16x8;
typedef __attribute__((ext_vector_type(4))) float f32x4;

__device__ __forceinline__ unsigned f2bf(float x) {
  unsigned u = __builtin_bit_cast(unsigned, x);
  return (u + 0x7fffu + ((u >> 16) & 1u)) >> 16;   // RNE, inputs are finite
}
__device__ __forceinline__ float fsig(float x)  { return 1.f / (1.f + __expf(-x)); }
__device__ __forceinline__ float ftanh(float x) { return 1.f - 2.f / (__expf(2.f * x) + 1.f); }

// ---- prep 1: weight fp32 -> bf16, layout unchanged (o, k=2i+tap contiguous) ----
__global__ void conv_weight_kernel(const float* __restrict__ w, unsigned* __restrict__ wb) {
  int idx = (blockIdx.x * 256 + threadIdx.x) * 4;    // 8192 blocks * 1024 floats = exact
  f32x4 v = *(const f32x4*)(w + idx);
  uint2 o;
  o.x = f2bf(v.x) | (f2bf(v.y) << 16);
  o.y = f2bf(v.z) | (f2bf(v.w) << 16);
  *(uint2*)(wb + (idx >> 1)) = o;
}

// ---- prep 2: Bd[n][k] bf16, k=2i+tap: tap0 = x[t-1] (z0h at t=0), tap1 = x[t] ----
// LDS-tiled transpose: read x along t (coalesced), write Bd along k (coalesced).
__global__ void build_bdup_kernel(const float* __restrict__ z1ss, const float* __restrict__ z0,
                                  unsigned* __restrict__ bd) {
  __shared__ float tile[32 * 34];                    // [ii][j], j in [0,33) = t0-1..t0+31
  const int tid = threadIdx.x;
  const int n0 = blockIdx.x * 32;                    // 256 n-tiles (never cross batch)
  const int i0 = blockIdx.y * 32;                    // 32 i-tiles
  const int b  = n0 >> 10;
  const int t0 = n0 & 1023;
  const int ii = tid >> 3, js = tid & 7;
  const float* zrow = z1ss + (b * 2048 + i0 + ii) * 1024;
  const float z0v = z0[b * 2048 + i0 + ii];
#pragma unroll
  for (int p = 0; p < 5; ++p) {
    int j = js + p * 8;
    if (j < 33) {
      int gt = t0 - 1 + j;
      tile[ii * 34 + j] = (gt < 0) ? z0v : zrow[gt];
    }
  }
  __syncthreads();
  const int i2 = tid & 31, ts = tid >> 5;
#pragma unroll
  for (int p = 0; p < 4; ++p) {
    int tt = ts + p * 8;
    float prev = tile[i2 * 34 + tt];                 // x[t-1] (or z0h)
    float cur  = tile[i2 * 34 + tt + 1];             // x[t]
    bd[(n0 + tt) * 1024 + i0 + i2] = f2bf(prev) | (f2bf(cur) << 16);  // shorts 2i / 2i+1
  }
}

// ---- GEMM + fused LSTM epilogue ----
// Block: 128 A-rows (row r = g*32+cc -> weight row g*1024+c0+cc) x 256 n-cols, BK=32.
// Wave w owns n-slice [w*64, w*64+64): per slab 32 MFMA, 12 ds_read_b128.
__launch_bounds__(256, 2)
__global__ void lstm_gemm_kernel(const unsigned short* __restrict__ Wb,
                                 const unsigned short* __restrict__ Bd,
                                 const float* __restrict__ uss,
                                 const float* __restrict__ z1ss,
                                 const float* __restrict__ z0,
                                 const float* __restrict__ bias,
                                 float* __restrict__ out) {
  __shared__ unsigned short Asm_[128 * LDA];   // 10.0 KB
  __shared__ unsigned short Bsm_[256 * LDB];   // 20.0 KB
  const int tid  = threadIdx.x;
  const int wave = tid >> 6, lane = tid & 63;
  const int l15  = lane & 15, quad = lane >> 4;
  const int c0 = blockIdx.y * 32;
  const int n0 = blockIdx.x * 256;

  // staging: thread -> (row = tid>>2 [+p*64], 16B chunk = tid&3); 64B-contig global segments
  const int srow = tid >> 2;
  const int schk = (tid & 3) * 8;              // short offset
  const unsigned short* asrc[2];
  const unsigned short* bsrc[4];
#pragma unroll
  for (int p = 0; p < 2; ++p) {
    int row = srow + p * 64;
    asrc[p] = Wb + ((row >> 5) * 1024 + c0 + (row & 31)) * K2 + schk;
  }
#pragma unroll
  for (int p = 0; p < 4; ++p)
    bsrc[p] = Bd + (n0 + srow + p * 64) * K2 + schk;

  f32x4 acc[4][2][4];
#pragma unroll
  for (int g = 0; g < 4; ++g)
#pragma unroll
    for (int mt = 0; mt < 2; ++mt)
#pragma unroll
      for (int nt = 0; nt < 4; ++nt)
        acc[g][mt][nt] = (f32x4){0.f, 0.f, 0.f, 0.f};

  for (int k0 = 0; k0 < K2; k0 += 32) {
    uint4 ar[2], br[4];
#pragma unroll
    for (int p = 0; p < 2; ++p) ar[p] = *(const uint4*)(asrc[p] + k0);
#pragma unroll
    for (int p = 0; p < 4; ++p) br[p] = *(const uint4*)(bsrc[p] + k0);
    __syncthreads();
#pragma unroll
    for (int p = 0; p < 2; ++p)
      *(uint4*)(Asm_ + (srow + p * 64) * LDA + schk) = ar[p];
#pragma unroll
    for (int p = 0; p < 4; ++p)
      *(uint4*)(Bsm_ + (srow + p * 64) * LDB + schk) = br[p];
    __syncthreads();

    bf16x8 bf[4];
#pragma unroll
    for (int nt = 0; nt < 4; ++nt)
      bf[nt] = *(const bf16x8*)(Bsm_ + (wave * 64 + nt * 16 + l15) * LDB + quad * 8);
#pragma unroll
    for (int g = 0; g < 4; ++g) {
#pragma unroll
      for (int mt = 0; mt < 2; ++mt) {
        bf16x8 af = *(const bf16x8*)(Asm_ + (g * 32 + mt * 16 + l15) * LDA + quad * 8);
#pragma unroll
        for (int nt = 0; nt < 4; ++nt)
          acc[g][mt][nt] = __builtin_amdgcn_mfma_f32_16x16x32_bf16(af, bf[nt], acc[g][mt][nt], 0, 0, 0);
      }
    }
  }

  // epilogue: C/D layout col=lane&15 (n), row=quad*4+reg (m); all 4 gates register-local
#pragma unroll
  for (int mt = 0; mt < 2; ++mt) {
#pragma unroll
    for (int r = 0; r < 4; ++r) {
      const int c = c0 + mt * 16 + quad * 4 + r;
      const float bv0 = bias[c], bv1 = bias[1024 + c], bv2 = bias[2048 + c], bv3 = bias[3072 + c];
#pragma unroll
      for (int nt = 0; nt < 4; ++nt) {
        const int n = n0 + wave * 64 + nt * 16 + l15;
        const int b = n >> 10, t = n & 1023;
        const int ub = b * 4194304 + c * 1024 + t;   // uss[b][g*1024+c][t], gate stride 1048576
        float p0 = acc[0][mt][nt][r] + uss[ub]           + bv0;
        float p1 = acc[1][mt][nt][r] + uss[ub + 1048576] + bv1;
        float p2 = acc[2][mt][nt][r] + uss[ub + 2097152] + bv2;
        float p3 = acc[3][mt][nt][r] + uss[ub + 3145728] + bv3;
        float it = fsig(p0), ot = fsig(p1), g_ = ftanh(p2), ft = fsig(p3);
        float zc = t ? z1ss[(b * 2048 + 1024 + c) * 1024 + t - 1]
                     : z0[b * 2048 + 1024 + c];
        float ct = ft * zc + it * g_;
        float ht = ot * ftanh(ct);
        const int ob = (b * 2048 + c) * 1024 + t;
        out[ob] = ht;
        out[ob + 1048576] = ct;
      }
    }
  }
}

// ---- slow-but-correct fallback if ws too small ----
__global__ void naive_kernel(const float* __restrict__ z1ss, const float* __restrict__ uss,
                             const float* __restrict__ z0, const float* __restrict__ w,
                             const float* __restrict__ bias, float* __restrict__ out) {
  int idx = blockIdx.x * 256 + threadIdx.x;          // (b,c,t)
  int b = idx >> 20, c = (idx >> 10) & 1023, t = idx & 1023;
  float s0 = 0.f, s1 = 0.f, s2 = 0.f, s3 = 0.f;
  const float* xb = z1ss + b * 2097152;
  for (int i = 0; i < 1024; ++i) {
    float cur  = xb[i * 1024 + t];
    float prev = t ? xb[i * 1024 + t - 1] : z0[b * 2048 + i];
    const float* wr = w + c * 2048 + i * 2;
    s0 += wr[0]       * prev + wr[1]       * cur;
    s1 += wr[2097152] * prev + wr[2097153] * cur;
    s2 += wr[4194304] * prev + wr[4194305] * cur;
    s3 += wr[6291456] * prev + wr[6291457] * cur;
  }
  int ub = b * 4194304 + c * 1024 + t;
  float p0 = s0 + uss[ub]           + bias[c];
  float p1 = s1 + uss[ub + 1048576] + bias[1024 + c];
  float p2 = s2 + uss[ub + 2097152] + bias[2048 + c];
  float p3 = s3 + uss[ub + 3145728] + bias[3072 + c];
  float it = fsig(p0), ot = fsig(p1), g_ = ftanh(p2), ft = fsig(p3);
  float zc = t ? z1ss[(b * 2048 + 1024 + c) * 1024 + t - 1] : z0[b * 2048 + 1024 + c];
  float ct = ft * zc + it * g_;
  float ht = ot * ftanh(ct);
  int ob = (b * 2048 + c) * 1024 + t;
  out[ob] = ht;
  out[ob + 1048576] = ct;
}

extern "C" void kernel_launch(void* const* d_in, const int* in_sizes, int n_in,
                              void* d_out, int out_size, void* d_ws, size_t ws_size,
                              hipStream_t stream) {
  const float* z1ss = (const float*)d_in[0];
  const float* uss  = (const float*)d_in[1];
  const float* z0   = (const float*)d_in[2];
  const float* w    = (const float*)d_in[3];
  const float* bias = (const float*)d_in[4];
  float* out = (float*)d_out;

  const size_t needWb = (size_t)4096 * 2048 * 2;   // 16 MB bf16 weight
  const size_t needBd = (size_t)NTOT * K2 * 2;     // 32 MB bf16 B matrix
  if (ws_size >= needWb + needBd) {
    unsigned short* Wb = (unsigned short*)d_ws;
    unsigned short* Bd = Wb + (size_t)4096 * 2048;
    conv_weight_kernel<<<8192, 256, 0, stream>>>(w, (unsigned*)Wb);
    build_bdup_kernel<<<dim3(256, 32), 256, 0, stream>>>(z1ss, z0, (unsigned*)Bd);
    lstm_gemm_kernel<<<dim3(32, 32), 256, 0, stream>>>(Wb, Bd, uss, z1ss, z0, bias, out);
  } else {
    naive_kernel<<<32768, 256, 0, stream>>>(z1ss, uss, z0, w, bias, out);
  }
}

// Round 2
// 447.443 us; speedup vs baseline: 1.7188x; 1.7188x over previous
//
#include <hip/hip_runtime.h>
#include <hip/hip_bf16.h>
#include <cstdint>

// Problem constants (bsz=8, h=1024, seq=1024, K=2 taps)
#define HSZ   1024
#define SEQ   1024
#define NTOT  8192      // bsz*seq
#define K2    2048      // 2*h (i,tap interleaved)

typedef __attribute__((ext_vector_type(8))) short bf16x8;
typedef __attribute__((ext_vector_type(4))) float f32x4;

__device__ __forceinline__ unsigned f2bf(float x) {
  unsigned u = __builtin_bit_cast(unsigned, x);
  return (u + 0x7fffu + ((u >> 16) & 1u)) >> 16;   // RNE, inputs are finite
}
__device__ __forceinline__ float fsig(float x)  { return 1.f / (1.f + __expf(-x)); }
__device__ __forceinline__ float ftanh(float x) { return 1.f - 2.f / (__expf(2.f * x) + 1.f); }

__device__ __forceinline__ void gload_lds16(const void* g, void* l) {
  __builtin_amdgcn_global_load_lds(
      (const __attribute__((address_space(1))) unsigned*)g,
      (__attribute__((address_space(3))) unsigned*)l, 16, 0, 0);
}

// ---- prep 1: weight fp32 -> bf16, layout unchanged (o, k=2i+tap contiguous) ----
__global__ void conv_weight_kernel(const float* __restrict__ w, unsigned* __restrict__ wb) {
  int idx = (blockIdx.x * 256 + threadIdx.x) * 4;    // 8192 blocks * 1024 floats = exact
  f32x4 v = *(const f32x4*)(w + idx);
  uint2 o;
  o.x = f2bf(v.x) | (f2bf(v.y) << 16);
  o.y = f2bf(v.z) | (f2bf(v.w) << 16);
  *(uint2*)(wb + (idx >> 1)) = o;
}

// ---- prep 2: Bd[n][k] bf16, k=2i+tap: tap0 = x[t-1] (z0h at t=0), tap1 = x[t] ----
__global__ void build_bdup_kernel(const float* __restrict__ z1ss, const float* __restrict__ z0,
                                  unsigned* __restrict__ bd) {
  __shared__ float tile[32 * 34];                    // [ii][j], j in [0,33) = t0-1..t0+31
  const int tid = threadIdx.x;
  const int n0 = blockIdx.x * 32;                    // 256 n-tiles (never cross batch)
  const int i0 = blockIdx.y * 32;                    // 32 i-tiles
  const int b  = n0 >> 10;
  const int t0 = n0 & 1023;
  const int ii = tid >> 3, js = tid & 7;
  const float* zrow = z1ss + (b * 2048 + i0 + ii) * 1024;
  const float z0v = z0[b * 2048 + i0 + ii];
#pragma unroll
  for (int p = 0; p < 5; ++p) {
    int j = js + p * 8;
    if (j < 33) {
      int gt = t0 - 1 + j;
      tile[ii * 34 + j] = (gt < 0) ? z0v : zrow[gt];
    }
  }
  __syncthreads();
  const int i2 = tid & 31, ts = tid >> 5;
#pragma unroll
  for (int p = 0; p < 4; ++p) {
    int tt = ts + p * 8;
    float prev = tile[i2 * 34 + tt];                 // x[t-1] (or z0h)
    float cur  = tile[i2 * 34 + tt + 1];             // x[t]
    bd[(n0 + tt) * 1024 + i0 + i2] = f2bf(prev) | (f2bf(cur) << 16);  // shorts 2i / 2i+1
  }
}

// ---- GEMM + fused LSTM epilogue (m97-style: global_load_lds + swizzled LDS) ----
// Block: 128 A-rows (row = g*32+cc -> weight row g*1024+c0+cc) x 128 n-cols, BK=32.
// Wave owns all 128 rows x 32 cols: acc[4][2][2] f32x4 = 64 regs/lane.
// LDS layout (A and B): 16B unit (row, slot) at byte (row*4+slot)*16,
//   slot = chunk ^ ((row>>1)&3)  -> DMA-compatible AND ds_read_b128 conflict-free.
__launch_bounds__(256, 3)
__global__ void lstm_gemm_kernel(const unsigned short* __restrict__ Wb,
                                 const unsigned short* __restrict__ Bd,
                                 const float* __restrict__ uss,
                                 const float* __restrict__ z1ss,
                                 const float* __restrict__ z0,
                                 const float* __restrict__ bias,
                                 float* __restrict__ out) {
  __shared__ unsigned short Asm_[128 * 32];   // 8 KB, swizzled
  __shared__ unsigned short Bsm_[128 * 32];   // 8 KB, swizzled
  const int tid  = threadIdx.x;
  const int wave = tid >> 6, lane = tid & 63;
  const int l15  = lane & 15, quad = lane >> 4;
  const int c0 = blockIdx.y * 32;
  const int n0 = blockIdx.x * 128;

  // staging: per wave 2 A-insts + 2 B-insts, each covers 16 rows x 32k (1024 B LDS)
  const unsigned short* agp[2];
  const unsigned short* bgp[2];
#pragma unroll
  for (int j = 0; j < 2; ++j) {
    const int idx = (wave * 2 + j) * 64 + lane;      // lds 16B-unit index
    const int row = idx >> 2;
    const int chunk = (idx & 3) ^ ((row >> 1) & 3);  // global k-chunk this lane fetches
    const int wrow = ((row >> 5) << 10) + c0 + (row & 31);
    agp[j] = Wb + (size_t)wrow * K2 + chunk * 8;
    bgp[j] = Bd + (size_t)(n0 + row) * K2 + chunk * 8;
  }
  unsigned short* ldsA[2] = { Asm_ + (wave * 2 + 0) * 512, Asm_ + (wave * 2 + 1) * 512 };
  unsigned short* ldsB[2] = { Bsm_ + (wave * 2 + 0) * 512, Bsm_ + (wave * 2 + 1) * 512 };

  // fragment read offset (shorts): row base l15*32, swizzled chunk slot
  const int swz  = (l15 >> 1) & 3;
  const int lofs = l15 * 32 + ((quad ^ swz) << 3);

  f32x4 acc[4][2][2];
#pragma unroll
  for (int g = 0; g < 4; ++g)
#pragma unroll
    for (int h = 0; h < 2; ++h)
#pragma unroll
      for (int nt = 0; nt < 2; ++nt)
        acc[g][h][nt] = (f32x4){0.f, 0.f, 0.f, 0.f};

  for (int k0 = 0; k0 < K2; k0 += 32) {
#pragma unroll
    for (int j = 0; j < 2; ++j) gload_lds16(agp[j] + k0, ldsA[j]);
#pragma unroll
    for (int j = 0; j < 2; ++j) gload_lds16(bgp[j] + k0, ldsB[j]);
    __syncthreads();                                  // drains vmcnt + barrier

    bf16x8 bf[2];
#pragma unroll
    for (int nt = 0; nt < 2; ++nt)
      bf[nt] = *(const bf16x8*)(Bsm_ + wave * 1024 + nt * 512 + lofs);
#pragma unroll
    for (int g = 0; g < 4; ++g)
#pragma unroll
      for (int h = 0; h < 2; ++h) {
        const int mt = g * 2 + h;
        bf16x8 af = *(const bf16x8*)(Asm_ + mt * 512 + lofs);
#pragma unroll
        for (int nt = 0; nt < 2; ++nt)
          acc[g][h][nt] = __builtin_amdgcn_mfma_f32_16x16x32_bf16(af, bf[nt], acc[g][h][nt], 0, 0, 0);
      }
    __syncthreads();                                  // protect LDS before next stage
  }

  // epilogue: C/D layout col=lane&15 (n), row=quad*4+reg (m); all 4 gates register-local
#pragma unroll
  for (int h = 0; h < 2; ++h) {
#pragma unroll
    for (int r = 0; r < 4; ++r) {
      const int c = c0 + h * 16 + quad * 4 + r;
      const float bv0 = bias[c], bv1 = bias[1024 + c], bv2 = bias[2048 + c], bv3 = bias[3072 + c];
#pragma unroll
      for (int nt = 0; nt < 2; ++nt) {
        const int n = n0 + wave * 32 + nt * 16 + l15;
        const int b = n >> 10, t = n & 1023;
        const int ub = b * 4194304 + c * 1024 + t;   // uss[b][g*1024+c][t], gate stride 1048576
        float p0 = acc[0][h][nt][r] + uss[ub]           + bv0;
        float p1 = acc[1][h][nt][r] + uss[ub + 1048576] + bv1;
        float p2 = acc[2][h][nt][r] + uss[ub + 2097152] + bv2;
        float p3 = acc[3][h][nt][r] + uss[ub + 3145728] + bv3;
        float it = fsig(p0), ot = fsig(p1), g_ = ftanh(p2), ft = fsig(p3);
        float zc = t ? z1ss[(b * 2048 + 1024 + c) * 1024 + t - 1]
                     : z0[b * 2048 + 1024 + c];
        float ct = ft * zc + it * g_;
        float ht = ot * ftanh(ct);
        const int ob = (b * 2048 + c) * 1024 + t;
        out[ob] = ht;
        out[ob + 1048576] = ct;
      }
    }
  }
}

// ---- slow-but-correct fallback if ws too small ----
__global__ void naive_kernel(const float* __restrict__ z1ss, const float* __restrict__ uss,
                             const float* __restrict__ z0, const float* __restrict__ w,
                             const float* __restrict__ bias, float* __restrict__ out) {
  int idx = blockIdx.x * 256 + threadIdx.x;          // (b,c,t)
  int b = idx >> 20, c = (idx >> 10) & 1023, t = idx & 1023;
  float s0 = 0.f, s1 = 0.f, s2 = 0.f, s3 = 0.f;
  const float* xb = z1ss + b * 2097152;
  for (int i = 0; i < 1024; ++i) {
    float cur  = xb[i * 1024 + t];
    float prev = t ? xb[i * 1024 + t - 1] : z0[b * 2048 + i];
    const float* wr = w + c * 2048 + i * 2;
    s0 += wr[0]       * prev + wr[1]       * cur;
    s1 += wr[2097152] * prev + wr[2097153] * cur;
    s2 += wr[4194304] * prev + wr[4194305] * cur;
    s3 += wr[6291456] * prev + wr[6291457] * cur;
  }
  int ub = b * 4194304 + c * 1024 + t;
  float p0 = s0 + uss[ub]           + bias[c];
  float p1 = s1 + uss[ub + 1048576] + bias[1024 + c];
  float p2 = s2 + uss[ub + 2097152] + bias[2048 + c];
  float p3 = s3 + uss[ub + 3145728] + bias[3072 + c];
  float it = fsig(p0), ot = fsig(p1), g_ = ftanh(p2), ft = fsig(p3);
  float zc = t ? z1ss[(b * 2048 + 1024 + c) * 1024 + t - 1] : z0[b * 2048 + 1024 + c];
  float ct = ft * zc + it * g_;
  float ht = ot * ftanh(ct);
  int ob = (b * 2048 + c) * 1024 + t;
  out[ob] = ht;
  out[ob + 1048576] = ct;
}

extern "C" void kernel_launch(void* const* d_in, const int* in_sizes, int n_in,
                              void* d_out, int out_size, void* d_ws, size_t ws_size,
                              hipStream_t stream) {
  const float* z1ss = (const float*)d_in[0];
  const float* uss  = (const float*)d_in[1];
  const float* z0   = (const float*)d_in[2];
  const float* w    = (const float*)d_in[3];
  const float* bias = (const float*)d_in[4];
  float* out = (float*)d_out;

  const size_t needWb = (size_t)4096 * 2048 * 2;   // 16 MB bf16 weight
  const size_t needBd = (size_t)NTOT * K2 * 2;     // 32 MB bf16 B matrix
  if (ws_size >= needWb + needBd) {
    unsigned short* Wb = (unsigned short*)d_ws;
    unsigned short* Bd = Wb + (size_t)4096 * 2048;
    conv_weight_kernel<<<8192, 256, 0, stream>>>(w, (unsigned*)Wb);
    build_bdup_kernel<<<dim3(256, 32), 256, 0, stream>>>(z1ss, z0, (unsigned*)Bd);
    lstm_gemm_kernel<<<dim3(64, 32), 256, 0, stream>>>(Wb, Bd, uss, z1ss, z0, bias, out);
  } else {
    naive_kernel<<<32768, 256, 0, stream>>>(z1ss, uss, z0, w, bias, out);
  }
}